// Round 2
// baseline (211.877 us; speedup 1.0000x reference)
//
#include <hip/hip_runtime.h>
#include <hip/hip_bf16.h>

// GAT MultiHeads, MI355X. N=4096, F_IN=256, H=8, D=16, HD=128.
// All inputs/outputs f32 (per reference dtypes); MFMA compute in bf16/f32-acc.
//
// Math identities (vs reference):
//  - logits[h,i,j] = f1[h,j] + f2[h,i]  (rank-1, never materialized)
//  - leaky_relu monotonic => unmasked row max usable; cancels in softmax ratio
//  - g in {0,1} => one exp per (h,i,j) shared by both graphs; mask = multiply
//  - fully-masked rows: denom clamp 1e-30 => output row 0 (matches densify)

#define NN 4096
#define LOG2E 1.44269504088896340736f

typedef short bf16x8 __attribute__((ext_vector_type(8)));
typedef float f32x4  __attribute__((ext_vector_type(4)));
typedef float f32x4e __attribute__((ext_vector_type(4)));

__device__ __forceinline__ unsigned short f2bf_rn(float f) {
  union { float f; unsigned int i; } v; v.f = f;
  unsigned int r = v.i + 0x7FFFu + ((v.i >> 16) & 1u);  // RTNE
  return (unsigned short)(r >> 16);
}
// pack two f32 -> two bf16 (truncate) in one v_perm_b32
__device__ __forceinline__ unsigned int pk_trunc(float lo, float hi) {
  return __builtin_amdgcn_perm(__float_as_uint(hi), __float_as_uint(lo), 0x07060302u);
}
// order-preserving f32<->u32 for atomicMax
__device__ __forceinline__ unsigned int enc_ord(float x) {
  unsigned int u = __float_as_uint(x);
  return (u >> 31) ? ~u : (u | 0x80000000u);
}
__device__ __forceinline__ float dec_ord(unsigned int u) {
  return __uint_as_float((u >> 31) ? (u ^ 0x80000000u) : ~u);
}

// ---- K0: one-time conversions. grid 512x256 ----
__global__ __launch_bounds__(256) void k_prep(
    const float* __restrict__ X, const float* __restrict__ Ww,
    const float* __restrict__ Wcat, const float* __restrict__ proj,
    const float* __restrict__ Wcb, const float* __restrict__ bias,
    const float* __restrict__ prb,
    unsigned short* __restrict__ Xb, unsigned short* __restrict__ WwT,
    unsigned short* __restrict__ WpT, float* __restrict__ bsum,
    unsigned int* __restrict__ Mf1bits)
{
  const int tid = blockIdx.x * 256 + threadIdx.x;  // 0..131071
  {  // X[4096][256] f32 -> bf16 (RTNE), 8 elements/thread
    const float4 a = *(const float4*)(X + (size_t)tid * 8);
    const float4 b = *(const float4*)(X + (size_t)tid * 8 + 4);
    uint4 o;
    o.x = (unsigned)f2bf_rn(a.x) | ((unsigned)f2bf_rn(a.y) << 16);
    o.y = (unsigned)f2bf_rn(a.z) | ((unsigned)f2bf_rn(a.w) << 16);
    o.z = (unsigned)f2bf_rn(b.x) | ((unsigned)f2bf_rn(b.y) << 16);
    o.w = (unsigned)f2bf_rn(b.z) | ((unsigned)f2bf_rn(b.w) << 16);
    *(uint4*)(Xb + (size_t)tid * 8) = o;
  }
  if (tid < 32768) {  // WwT[c][k] = Ww[k][c], bf16
    int c = tid & 127, k = tid >> 7;
    WwT[c * 256 + k] = f2bf_rn(Ww[k * 128 + c]);
  }
  if (tid < 65536) {  // WpT[c][k]: k<256 -> Wcat[k][c], else proj[k-256][c]
    int c = tid & 127, k = tid >> 7;
    float v = (k < 256) ? Wcat[k * 128 + c] : proj[(k - 256) * 128 + c];
    WpT[c * 512 + k] = f2bf_rn(v);
  }
  if (tid < 128) bsum[tid] = Wcb[tid] + bias[tid] + prb[tid];
  if (tid < 8) Mf1bits[tid] = 0u;
}

// ---- K1: score GEMM + f1/f2 + Mf1. grid 256 x 512 (8 waves = 8 heads) ----
__global__ __launch_bounds__(512) void k_score(
    const unsigned short* __restrict__ Xb, const unsigned short* __restrict__ WwT,
    const float* __restrict__ Wb, const float* __restrict__ wu,
    const float* __restrict__ wv,
    unsigned short* __restrict__ scT, float* __restrict__ f1,
    float* __restrict__ f2, unsigned int* __restrict__ Mf1bits)
{
  const int n0 = blockIdx.x * 16;
  const int h = threadIdx.x >> 6, lane = threadIdx.x & 63;
  const int mr = lane & 15, grp = lane >> 4;
  const unsigned short* ap  = Xb  + (size_t)(n0 + mr) * 256;
  const unsigned short* bpp = WwT + (size_t)(h * 16 + mr) * 256;
  f32x4 acc = {0.f, 0.f, 0.f, 0.f};
  #pragma unroll
  for (int ks = 0; ks < 8; ++ks) {
    bf16x8 a = *(const bf16x8*)(ap  + ks * 32 + grp * 8);
    bf16x8 b = *(const bf16x8*)(bpp + ks * 32 + grp * 8);
    acc = __builtin_amdgcn_mfma_f32_16x16x32_bf16(a, b, acc, 0, 0, 0);
  }
  const float wb = Wb[h * 16 + mr];
  float sc[4];
  #pragma unroll
  for (int r = 0; r < 4; ++r) sc[r] = acc[r] + wb;  // score[n0+grp*4+r][h*16+mr]

  uint2 st;  // scT[h*16+mr][n0+grp*4 .. +3] bf16
  st.x = (unsigned)f2bf_rn(sc[0]) | ((unsigned)f2bf_rn(sc[1]) << 16);
  st.y = (unsigned)f2bf_rn(sc[2]) | ((unsigned)f2bf_rn(sc[3]) << 16);
  *(uint2*)(scT + (size_t)(h * 16 + mr) * NN + n0 + grp * 4) = st;

  const float uw = wu[h * 16 + mr], vw = wv[h * 16 + mr];
  float t1[4], t2[4];
  #pragma unroll
  for (int r = 0; r < 4; ++r) { t1[r] = sc[r] * uw; t2[r] = sc[r] * vw; }
  #pragma unroll
  for (int m = 1; m < 16; m <<= 1) {
    #pragma unroll
    for (int r = 0; r < 4; ++r) {
      t1[r] += __shfl_xor(t1[r], m, 64);
      t2[r] += __shfl_xor(t2[r], m, 64);
    }
  }
  if (mr == 0) {
    f32x4e w1 = {t1[0], t1[1], t1[2], t1[3]};
    f32x4e w2 = {t2[0], t2[1], t2[2], t2[3]};
    *(f32x4e*)(f1 + h * NN + n0 + grp * 4) = w1;
    *(f32x4e*)(f2 + h * NN + n0 + grp * 4) = w2;
  }
  float mx = fmaxf(fmaxf(t1[0], t1[1]), fmaxf(t1[2], t1[3]));
  mx = fmaxf(mx, __shfl_xor(mx, 16, 64));
  mx = fmaxf(mx, __shfl_xor(mx, 32, 64));
  if (lane == 0) atomicMax(Mf1bits + h, enc_ord(mx));
}

// ---- K2: fused dual-graph masked softmax attention + output GEMM ----
// grid 256 (i-tiles) x 512 (wave = head). Masks read ONCE (L1-shared).
__global__ __launch_bounds__(512) void k_attn_out(
    const float* __restrict__ Dg, const float* __restrict__ Sg,
    const unsigned short* __restrict__ scT, const float* __restrict__ f1,
    const float* __restrict__ f2, const unsigned int* __restrict__ Mf1bits,
    const unsigned short* __restrict__ Xb, const unsigned short* __restrict__ WpT,
    const float* __restrict__ bsum, float* __restrict__ out)
{
  __shared__ unsigned short catT[16][520];  // [row][ S(128) | D(128) | X(256) ] bf16, +8 pad
  const int i0 = blockIdx.x * 16;
  const int tid = threadIdx.x;
  {  // stage X rows -> catT cols 256..511
    const int r = tid >> 5, f0 = (tid & 31) * 8;
    bf16x8 xv = *(const bf16x8*)(Xb + (size_t)(i0 + r) * 256 + f0);
    *(bf16x8*)(&catT[r][256 + f0]) = xv;
  }
  const int h = tid >> 6, lane = tid & 63;
  const int mr = lane & 15, grp = lane >> 4;

  const float f2v = f2[h * NN + i0 + mr];
  const float xm = f2v + dec_ord(Mf1bits[h]);
  const float mrow = fmaxf(xm, 0.3f * xm);  // lrelu(unmasked row max)
  const float mL = mrow * LOG2E;

  const float* f1h = f1 + h * NN;
  const float* drow = Dg + (size_t)(i0 + mr) * NN;
  const float* srow = Sg + (size_t)(i0 + mr) * NN;
  const unsigned short* bp = scT + (size_t)(h * 16 + mr) * NN;

  f32x4 accD = {0.f,0.f,0.f,0.f}, accS = {0.f,0.f,0.f,0.f};
  float dnD = 0.f, dnS = 0.f;

  for (int s = 0; s < 128; ++s) {
    const int j8 = s * 32 + grp * 8;
    f32x4e fA = *(const f32x4e*)(f1h + j8);
    f32x4e fB = *(const f32x4e*)(f1h + j8 + 4);
    f32x4e dA = *(const f32x4e*)(drow + j8);
    f32x4e dB = *(const f32x4e*)(drow + j8 + 4);
    f32x4e sA = *(const f32x4e*)(srow + j8);
    f32x4e sB = *(const f32x4e*)(srow + j8 + 4);
    bf16x8 bfrag = *(const bf16x8*)(bp + j8);
    float pd[8], ps[8];
    #pragma unroll
    for (int e = 0; e < 4; ++e) {
      float x = fA[e] + f2v;
      float w = fmaxf(x, 0.3f * x);
      float p = __builtin_amdgcn_exp2f(__builtin_fmaf(w, LOG2E, -mL));
      float eD = p * dA[e], eS = p * sA[e];
      dnD += eD; dnS += eS; pd[e] = eD; ps[e] = eS;
    }
    #pragma unroll
    for (int e = 0; e < 4; ++e) {
      float x = fB[e] + f2v;
      float w = fmaxf(x, 0.3f * x);
      float p = __builtin_amdgcn_exp2f(__builtin_fmaf(w, LOG2E, -mL));
      float eD = p * dB[e], eS = p * sB[e];
      dnD += eD; dnS += eS; pd[e + 4] = eD; ps[e + 4] = eS;
    }
    union { unsigned int u[4]; bf16x8 v; } AD, AS;
    #pragma unroll
    for (int q = 0; q < 4; ++q) {
      AD.u[q] = pk_trunc(pd[2 * q], pd[2 * q + 1]);
      AS.u[q] = pk_trunc(ps[2 * q], ps[2 * q + 1]);
    }
    accD = __builtin_amdgcn_mfma_f32_16x16x32_bf16(AD.v, bfrag, accD, 0, 0, 0);
    accS = __builtin_amdgcn_mfma_f32_16x16x32_bf16(AS.v, bfrag, accS, 0, 0, 0);
  }

  // row denominators: lane holds row (lane&15); sum the 4 k-groups
  dnD += __shfl_xor(dnD, 16, 64); dnD += __shfl_xor(dnD, 32, 64);
  dnS += __shfl_xor(dnS, 16, 64); dnS += __shfl_xor(dnS, 32, 64);

  // C layout: col=mr (d), row=grp*4+r (i). Normalize, write cat (S | D) bf16.
  #pragma unroll
  for (int r = 0; r < 4; ++r) {
    const int row = grp * 4 + r;
    const float dD = __shfl(dnD, row, 16);
    const float dS = __shfl(dnS, row, 16);
    const float vS = accS[r] * __builtin_amdgcn_rcpf(fmaxf(dS, 1e-30f));
    const float vD = accD[r] * __builtin_amdgcn_rcpf(fmaxf(dD, 1e-30f));
    catT[row][h * 16 + mr]       = f2bf_rn(vS);
    catT[row][128 + h * 16 + mr] = f2bf_rn(vD);
  }
  __syncthreads();

  // phase B: out[16][128] = catT[16][512] @ W'[512][128] + bsum
  f32x4 o = {0.f, 0.f, 0.f, 0.f};
  const unsigned short* wp = WpT + (size_t)(h * 16 + mr) * 512;
  #pragma unroll
  for (int ks = 0; ks < 16; ++ks) {
    bf16x8 a = *(const bf16x8*)(&catT[mr][ks * 32 + grp * 8]);
    bf16x8 b = *(const bf16x8*)(wp + ks * 32 + grp * 8);
    o = __builtin_amdgcn_mfma_f32_16x16x32_bf16(a, b, o, 0, 0, 0);
  }
  const float bs = bsum[h * 16 + mr];
  #pragma unroll
  for (int r = 0; r < 4; ++r)
    out[(size_t)(i0 + grp * 4 + r) * 128 + h * 16 + mr] = o[r] + bs;
}

extern "C" void kernel_launch(void* const* d_in, const int* in_sizes, int n_in,
                              void* d_out, int out_size, void* d_ws, size_t ws_size,
                              hipStream_t stream) {
  const float* X    = (const float*)d_in[0];
  const float* Dg   = (const float*)d_in[1];
  const float* Sg   = (const float*)d_in[2];
  const float* Ww   = (const float*)d_in[3];
  const float* Wb   = (const float*)d_in[4];
  const float* wu   = (const float*)d_in[5];
  const float* wv   = (const float*)d_in[6];
  const float* Wcat = (const float*)d_in[7];
  const float* Wcb  = (const float*)d_in[8];
  const float* bias = (const float*)d_in[9];
  const float* proj = (const float*)d_in[10];
  const float* prb  = (const float*)d_in[11];
  float* out = (float*)d_out;

  char* ws = (char*)d_ws;
  unsigned short* Xb   = (unsigned short*)(ws);              // 2 MB
  unsigned short* scT  = (unsigned short*)(ws + 0x200000);   // 1 MB
  float*          f1   = (float*)(ws + 0x300000);            // 128 KB
  float*          f2   = (float*)(ws + 0x320000);            // 128 KB
  unsigned short* WwT  = (unsigned short*)(ws + 0x340000);   // 64 KB
  unsigned short* WpT  = (unsigned short*)(ws + 0x350000);   // 128 KB
  float*          bsum = (float*)(ws + 0x370000);            // 512 B
  unsigned int*   Mf1b = (unsigned int*)(ws + 0x370200);     // 32 B

  k_prep<<<dim3(512), dim3(256), 0, stream>>>(X, Ww, Wcat, proj, Wcb, bias, prb,
                                              Xb, WwT, WpT, bsum, Mf1b);
  k_score<<<dim3(256), dim3(512), 0, stream>>>(Xb, WwT, Wb, wu, wv, scT, f1, f2, Mf1b);
  k_attn_out<<<dim3(256), dim3(512), 0, stream>>>(Dg, Sg, scT, f1, f2, Mf1b,
                                                  Xb, WpT, bsum, out);
}

// Round 3
// 104.489 us; speedup vs baseline: 2.0278x; 2.0278x over previous
//
#include <hip/hip_runtime.h>
#include <hip/hip_bf16.h>

// GAT MultiHeads, MI355X. N=4096, F_IN=256, H=8, D=16, HD=128.
// All inputs/outputs f32; MFMA compute in bf16 / f32-acc.
//
// Math identities (vs reference):
//  - logits[h,i,j] = f1[h,j] + f2[h,i]  (rank-1, never materialized)
//  - exp(lrelu(x)) is piecewise-separable: x>=0 -> E1[j]*A[i], x<0 -> E3[j]*B[i]
//    with E1=e^f1, E3=e^{0.3 f1}, A=e^f2, B=e^{0.3 f2}; select via E1[j] >= e^{-f2[i]}
//  - no max-subtraction needed: logits bounded (|x| < ~4), softmax ratio invariant
//  - g in {0,1} => shared exp value, mask applied as multiply
//  - fully-masked rows: denom clamp 1e-30 => output row 0 (matches densify)

#define NN 4096
#define LOG2E 1.44269504088896340736f

typedef short bf16x8 __attribute__((ext_vector_type(8)));
typedef float f32x4  __attribute__((ext_vector_type(4)));

__device__ __forceinline__ unsigned short f2bf_rn(float f) {
  union { float f; unsigned int i; } v; v.f = f;
  unsigned int r = v.i + 0x7FFFu + ((v.i >> 16) & 1u);  // RTNE
  return (unsigned short)(r >> 16);
}
// pack two f32 -> two bf16 (truncate) in one v_perm_b32
__device__ __forceinline__ unsigned int pk_trunc(float lo, float hi) {
  return __builtin_amdgcn_perm(__float_as_uint(hi), __float_as_uint(lo), 0x07060302u);
}

// ---- K0: one-time conversions. grid 512x256 ----
__global__ __launch_bounds__(256) void k_prep(
    const float* __restrict__ X, const float* __restrict__ Ww,
    const float* __restrict__ Wcat, const float* __restrict__ proj,
    const float* __restrict__ Wcb, const float* __restrict__ bias,
    const float* __restrict__ prb,
    unsigned short* __restrict__ Xb, unsigned short* __restrict__ WwT,
    unsigned short* __restrict__ WpT, float* __restrict__ bsum)
{
  const int tid = blockIdx.x * 256 + threadIdx.x;  // 0..131071
  {  // X[4096][256] f32 -> bf16 (RTNE), 8 elements/thread
    const float4 a = *(const float4*)(X + (size_t)tid * 8);
    const float4 b = *(const float4*)(X + (size_t)tid * 8 + 4);
    uint4 o;
    o.x = (unsigned)f2bf_rn(a.x) | ((unsigned)f2bf_rn(a.y) << 16);
    o.y = (unsigned)f2bf_rn(a.z) | ((unsigned)f2bf_rn(a.w) << 16);
    o.z = (unsigned)f2bf_rn(b.x) | ((unsigned)f2bf_rn(b.y) << 16);
    o.w = (unsigned)f2bf_rn(b.z) | ((unsigned)f2bf_rn(b.w) << 16);
    *(uint4*)(Xb + (size_t)tid * 8) = o;
  }
  if (tid < 32768) {  // WwT[c][k] = Ww[k][c], bf16
    int c = tid & 127, k = tid >> 7;
    WwT[c * 256 + k] = f2bf_rn(Ww[k * 128 + c]);
  }
  if (tid < 65536) {  // WpT[c][k]: k<256 -> Wcat[k][c], else proj[k-256][c]
    int c = tid & 127, k = tid >> 7;
    float v = (k < 256) ? Wcat[k * 128 + c] : proj[(k - 256) * 128 + c];
    WpT[c * 512 + k] = f2bf_rn(v);
  }
  if (tid < 128) bsum[tid] = Wcb[tid] + bias[tid] + prb[tid];
}

// ---- K1: score GEMM + f2 + exp tables. grid 256 x 512 (8 waves = 8 heads) ----
__global__ __launch_bounds__(512) void k_score(
    const unsigned short* __restrict__ Xb, const unsigned short* __restrict__ WwT,
    const float* __restrict__ Wb, const float* __restrict__ wu,
    const float* __restrict__ wv,
    unsigned short* __restrict__ scT, float* __restrict__ f2,
    float* __restrict__ EE)
{
  const int n0 = blockIdx.x * 16;
  const int h = threadIdx.x >> 6, lane = threadIdx.x & 63;
  const int mr = lane & 15, grp = lane >> 4;
  const unsigned short* ap  = Xb  + (size_t)(n0 + mr) * 256;
  const unsigned short* bpp = WwT + (size_t)(h * 16 + mr) * 256;
  f32x4 acc = {0.f, 0.f, 0.f, 0.f};
  #pragma unroll
  for (int ks = 0; ks < 8; ++ks) {
    bf16x8 a = *(const bf16x8*)(ap  + ks * 32 + grp * 8);
    bf16x8 b = *(const bf16x8*)(bpp + ks * 32 + grp * 8);
    acc = __builtin_amdgcn_mfma_f32_16x16x32_bf16(a, b, acc, 0, 0, 0);
  }
  const float wb = Wb[h * 16 + mr];
  float sc[4];
  #pragma unroll
  for (int r = 0; r < 4; ++r) sc[r] = acc[r] + wb;  // score[n0+grp*4+r][h*16+mr]

  uint2 st;  // scT[h*16+mr][n0+grp*4 .. +3] bf16
  st.x = (unsigned)f2bf_rn(sc[0]) | ((unsigned)f2bf_rn(sc[1]) << 16);
  st.y = (unsigned)f2bf_rn(sc[2]) | ((unsigned)f2bf_rn(sc[3]) << 16);
  *(uint2*)(scT + (size_t)(h * 16 + mr) * NN + n0 + grp * 4) = st;

  const float uw = wu[h * 16 + mr], vw = wv[h * 16 + mr];
  float t1[4], t2[4];
  #pragma unroll
  for (int r = 0; r < 4; ++r) { t1[r] = sc[r] * uw; t2[r] = sc[r] * vw; }
  #pragma unroll
  for (int m = 1; m < 16; m <<= 1) {
    #pragma unroll
    for (int r = 0; r < 4; ++r) {
      t1[r] += __shfl_xor(t1[r], m, 64);
      t2[r] += __shfl_xor(t2[r], m, 64);
    }
  }
  if (mr == 0) {
    *(float4*)(f2 + h * NN + n0 + grp * 4) = make_float4(t2[0], t2[1], t2[2], t2[3]);
    float4 ea, eb;  // EE[h][n] = {e^f1, e^{0.3 f1}} interleaved
    ea.x = __builtin_amdgcn_exp2f(t1[0] * LOG2E);
    ea.y = __builtin_amdgcn_exp2f(0.3f * t1[0] * LOG2E);
    ea.z = __builtin_amdgcn_exp2f(t1[1] * LOG2E);
    ea.w = __builtin_amdgcn_exp2f(0.3f * t1[1] * LOG2E);
    eb.x = __builtin_amdgcn_exp2f(t1[2] * LOG2E);
    eb.y = __builtin_amdgcn_exp2f(0.3f * t1[2] * LOG2E);
    eb.z = __builtin_amdgcn_exp2f(t1[3] * LOG2E);
    eb.w = __builtin_amdgcn_exp2f(0.3f * t1[3] * LOG2E);
    float* ep = EE + h * (NN * 2) + (n0 + grp * 4) * 2;
    *(float4*)(ep)     = ea;
    *(float4*)(ep + 4) = eb;
  }
}

// ---- K2: fused dual-graph masked softmax attention + output GEMM ----
// grid 256 (i-tiles) x 512 (8 waves = 8 heads). Masks LDS-staged once per
// block (double-buffered 256-col windows), shared by all head-waves.
__global__ __launch_bounds__(512) void k_attn_out(
    const float* __restrict__ Dg, const float* __restrict__ Sg,
    const unsigned short* __restrict__ scT, const float* __restrict__ EE,
    const float* __restrict__ f2, const unsigned short* __restrict__ Xb,
    const unsigned short* __restrict__ WpT, const float* __restrict__ bsum,
    float* __restrict__ out)
{
  __shared__ float win[2][2][16][260];      // [buf][graph][row][j-window+pad]
  __shared__ unsigned short catT[16][520];  // [row][ S(128) | D(128) | X(256) ]
  const int i0 = blockIdx.x * 16;
  const int tid = threadIdx.x;

  {  // stage X rows -> catT cols 256..511
    const int r = tid >> 5, x0 = (tid & 31) * 8;
    *(bf16x8*)(&catT[r][256 + x0]) = *(const bf16x8*)(Xb + (size_t)(i0 + r) * 256 + x0);
  }

  // staging role: 2 graphs x 16 rows x 16 chunk-cols, 4x16B chunks per thread
  const int sg = tid >> 8;
  const int sr = (tid >> 4) & 15;
  const int sc = tid & 15;
  const float* gsrc = (sg ? Sg : Dg) + (size_t)(i0 + sr) * NN + sc * 4;
  float4 st0, st1, st2, st3;
  auto LOADW = [&](int w) {
    const float* p = gsrc + w * 256;
    st0 = *(const float4*)(p);
    st1 = *(const float4*)(p + 64);
    st2 = *(const float4*)(p + 128);
    st3 = *(const float4*)(p + 192);
  };
  auto WRITEW = [&](int w) {
    float* p = &win[w & 1][sg][sr][sc * 4];
    *(float4*)(p)       = st0;
    *(float4*)(p + 64)  = st1;
    *(float4*)(p + 128) = st2;
    *(float4*)(p + 192) = st3;
  };

  const int h = tid >> 6, lane = tid & 63;
  const int mr = lane & 15, grp = lane >> 4;

  const float f2v = f2[h * NN + i0 + mr];
  const float Af = __builtin_amdgcn_exp2f(f2v * LOG2E);          // e^{f2}
  const float Bf = __builtin_amdgcn_exp2f(0.3f * f2v * LOG2E);   // e^{0.3 f2}
  const float Tf = __builtin_amdgcn_exp2f(-f2v * LOG2E);         // e^{-f2}

  const float* eeh = EE + h * (NN * 2);
  const unsigned short* bp = scT + (size_t)(h * 16 + mr) * NN;

  f32x4 accD = {0.f,0.f,0.f,0.f}, accS = {0.f,0.f,0.f,0.f};
  float dnD = 0.f, dnS = 0.f;

  LOADW(0);
  WRITEW(0);
  LOADW(1);
  __syncthreads();

  for (int w = 0; w < 16; ++w) {
    const float* dwin = &win[w & 1][0][mr][0];
    const float* swin = &win[w & 1][1][mr][0];
    const float* eew  = eeh + w * 512;
    const unsigned short* bpw = bp + w * 256;
    #pragma unroll
    for (int it = 0; it < 8; ++it) {
      const int jl = it * 32 + grp * 8;
      const f32x4 d0 = *(const f32x4*)(dwin + jl);
      const f32x4 d1 = *(const f32x4*)(dwin + jl + 4);
      const f32x4 s0 = *(const f32x4*)(swin + jl);
      const f32x4 s1 = *(const f32x4*)(swin + jl + 4);
      const f32x4 e0 = *(const f32x4*)(eew + jl * 2);
      const f32x4 e1 = *(const f32x4*)(eew + jl * 2 + 4);
      const f32x4 e2 = *(const f32x4*)(eew + jl * 2 + 8);
      const f32x4 e3 = *(const f32x4*)(eew + jl * 2 + 12);
      const bf16x8 bfrag = *(const bf16x8*)(bpw + jl);
      float pd[8], ps[8];
      #pragma unroll
      for (int e = 0; e < 8; ++e) {
        const f32x4 ev = (e < 2) ? e0 : (e < 4) ? e1 : (e < 6) ? e2 : e3;
        const float E1 = ev[(e & 1) * 2];
        const float E3 = ev[(e & 1) * 2 + 1];
        const bool sel = E1 >= Tf;                  // f1[j]+f2[i] >= 0
        const float q = (sel ? E1 : E3) * (sel ? Af : Bf);
        const float dmv = (e < 4) ? d0[e & 3] : d1[e & 3];
        const float smv = (e < 4) ? s0[e & 3] : s1[e & 3];
        const float eD = q * dmv;
        const float eS = q * smv;
        dnD += eD; dnS += eS;
        pd[e] = eD; ps[e] = eS;
      }
      union { unsigned int u[4]; bf16x8 v; } AD, AS;
      #pragma unroll
      for (int q2 = 0; q2 < 4; ++q2) {
        AD.u[q2] = pk_trunc(pd[2 * q2], pd[2 * q2 + 1]);
        AS.u[q2] = pk_trunc(ps[2 * q2], ps[2 * q2 + 1]);
      }
      accD = __builtin_amdgcn_mfma_f32_16x16x32_bf16(AD.v, bfrag, accD, 0, 0, 0);
      accS = __builtin_amdgcn_mfma_f32_16x16x32_bf16(AS.v, bfrag, accS, 0, 0, 0);
    }
    if (w < 15) {
      __syncthreads();       // buf[(w+1)&1] fully consumed (in window w-1)
      WRITEW(w + 1);
      if (w < 14) LOADW(w + 2);   // in flight during compute of w+1
      __syncthreads();       // buf[(w+1)&1] ready
    }
  }

  // row denominators: sum the 4 k-groups
  dnD += __shfl_xor(dnD, 16, 64); dnD += __shfl_xor(dnD, 32, 64);
  dnS += __shfl_xor(dnS, 16, 64); dnS += __shfl_xor(dnS, 32, 64);

  // C layout: col=mr (d), row=grp*4+r (i). Normalize, write cat (S | D) bf16.
  #pragma unroll
  for (int r = 0; r < 4; ++r) {
    const int row = grp * 4 + r;
    const float dD = __shfl(dnD, row, 16);
    const float dS = __shfl(dnS, row, 16);
    const float vS = accS[r] * __builtin_amdgcn_rcpf(fmaxf(dS, 1e-30f));
    const float vD = accD[r] * __builtin_amdgcn_rcpf(fmaxf(dD, 1e-30f));
    catT[row][h * 16 + mr]       = f2bf_rn(vS);
    catT[row][128 + h * 16 + mr] = f2bf_rn(vD);
  }
  __syncthreads();

  // phase B: out[16][128] = catT[16][512] @ W'[512][128] + bsum
  f32x4 o = {0.f, 0.f, 0.f, 0.f};
  const unsigned short* wp = WpT + (size_t)(h * 16 + mr) * 512;
  #pragma unroll
  for (int ks = 0; ks < 16; ++ks) {
    bf16x8 a = *(const bf16x8*)(&catT[mr][ks * 32 + grp * 8]);
    bf16x8 b = *(const bf16x8*)(wp + ks * 32 + grp * 8);
    o = __builtin_amdgcn_mfma_f32_16x16x32_bf16(a, b, o, 0, 0, 0);
  }
  const float bs = bsum[h * 16 + mr];
  #pragma unroll
  for (int r = 0; r < 4; ++r)
    out[(size_t)(i0 + grp * 4 + r) * 128 + h * 16 + mr] = o[r] + bs;
}

extern "C" void kernel_launch(void* const* d_in, const int* in_sizes, int n_in,
                              void* d_out, int out_size, void* d_ws, size_t ws_size,
                              hipStream_t stream) {
  const float* X    = (const float*)d_in[0];
  const float* Dg   = (const float*)d_in[1];
  const float* Sg   = (const float*)d_in[2];
  const float* Ww   = (const float*)d_in[3];
  const float* Wb   = (const float*)d_in[4];
  const float* wu   = (const float*)d_in[5];
  const float* wv   = (const float*)d_in[6];
  const float* Wcat = (const float*)d_in[7];
  const float* Wcb  = (const float*)d_in[8];
  const float* bias = (const float*)d_in[9];
  const float* proj = (const float*)d_in[10];
  const float* prb  = (const float*)d_in[11];
  float* out = (float*)d_out;

  char* ws = (char*)d_ws;
  unsigned short* Xb   = (unsigned short*)(ws);              // 2 MB
  unsigned short* scT  = (unsigned short*)(ws + 0x200000);   // 1 MB
  float*          f2   = (float*)(ws + 0x300000);            // 128 KB
  float*          EE   = (float*)(ws + 0x320000);            // 256 KB
  unsigned short* WwT  = (unsigned short*)(ws + 0x360000);   // 64 KB
  unsigned short* WpT  = (unsigned short*)(ws + 0x370000);   // 128 KB
  float*          bsum = (float*)(ws + 0x390000);            // 512 B

  k_prep<<<dim3(512), dim3(256), 0, stream>>>(X, Ww, Wcat, proj, Wcb, bias, prb,
                                              Xb, WwT, WpT, bsum);
  k_score<<<dim3(256), dim3(512), 0, stream>>>(Xb, WwT, Wb, wu, wv, scT, f2, EE);
  k_attn_out<<<dim3(256), dim3(512), 0, stream>>>(Dg, Sg, scT, EE, f2,
                                                  Xb, WpT, bsum, out);
}

// Round 4
// 99.047 us; speedup vs baseline: 2.1392x; 1.0549x over previous
//
#include <hip/hip_runtime.h>
#include <hip/hip_bf16.h>

// GAT MultiHeads, MI355X. N=4096, F_IN=256, H=8, D=16, HD=128.
// All inputs/outputs f32; MFMA compute in bf16 / f32-acc.
//
// Math identities (vs reference):
//  - logits[h,i,j] = f1[h,j] + f2[h,i]  (rank-1, never materialized)
//  - exp(lrelu(x)) piecewise-separable: x>=0 -> E1[j]*A[i], x<0 -> E3[j]*B[i],
//    E1=e^f1, E3=e^{0.3 f1}, A=e^f2, B=e^{0.3 f2}; select via E1[j] >= e^{-f2[i]}
//  - no max-subtraction: logits bounded (|x| < ~4), softmax ratio invariant
//  - g in {0,1} => mask as bit; one shared q per (h,i,j), cndmask per graph
//  - denominators = P @ ones via MFMA (free pipe), every lane gets its row sum
//  - fully-masked rows: denom clamp 1e-30 => output row 0 (matches densify)

#define NN 4096
#define LOG2E 1.44269504088896340736f

typedef short bf16x8 __attribute__((ext_vector_type(8)));
typedef float f32x4  __attribute__((ext_vector_type(4)));
typedef unsigned long long u64x4 __attribute__((ext_vector_type(4)));
typedef unsigned long long u64x2 __attribute__((ext_vector_type(2)));

__device__ __forceinline__ unsigned short f2bf_rn(float f) {
  union { float f; unsigned int i; } v; v.f = f;
  unsigned int r = v.i + 0x7FFFu + ((v.i >> 16) & 1u);  // RTNE
  return (unsigned short)(r >> 16);
}
// pack two f32 -> two bf16 (truncate) in one v_perm_b32
__device__ __forceinline__ unsigned int pk_trunc(float lo, float hi) {
  return __builtin_amdgcn_perm(__float_as_uint(hi), __float_as_uint(lo), 0x07060302u);
}
// {E3,E1} bf16 pair from f1 value
__device__ __forceinline__ unsigned int epack(float f1v) {
  float E1 = __builtin_amdgcn_exp2f(f1v * LOG2E);
  float E3 = __builtin_amdgcn_exp2f(0.3f * f1v * LOG2E);
  return ((unsigned)f2bf_rn(E3) << 16) | (unsigned)f2bf_rn(E1);
}

// ---- K0: one-time conversions. grid 512x256 ----
__global__ __launch_bounds__(256) void k_prep(
    const float* __restrict__ X, const float* __restrict__ Ww,
    const float* __restrict__ Wcat, const float* __restrict__ proj,
    const float* __restrict__ Wcb, const float* __restrict__ bias,
    const float* __restrict__ prb,
    unsigned short* __restrict__ Xb, unsigned short* __restrict__ WwT,
    unsigned short* __restrict__ WpT, float* __restrict__ bsum)
{
  const int tid = blockIdx.x * 256 + threadIdx.x;  // 0..131071
  {  // X[4096][256] f32 -> bf16 (RTNE), 8 elements/thread
    const float4 a = *(const float4*)(X + (size_t)tid * 8);
    const float4 b = *(const float4*)(X + (size_t)tid * 8 + 4);
    uint4 o;
    o.x = (unsigned)f2bf_rn(a.x) | ((unsigned)f2bf_rn(a.y) << 16);
    o.y = (unsigned)f2bf_rn(a.z) | ((unsigned)f2bf_rn(a.w) << 16);
    o.z = (unsigned)f2bf_rn(b.x) | ((unsigned)f2bf_rn(b.y) << 16);
    o.w = (unsigned)f2bf_rn(b.z) | ((unsigned)f2bf_rn(b.w) << 16);
    *(uint4*)(Xb + (size_t)tid * 8) = o;
  }
  if (tid < 32768) {  // WwT[c][k] = Ww[k][c], bf16
    int c = tid & 127, k = tid >> 7;
    WwT[c * 256 + k] = f2bf_rn(Ww[k * 128 + c]);
  }
  if (tid < 65536) {  // WpT[c][k]: k<256 -> Wcat[k][c], else proj[k-256][c]
    int c = tid & 127, k = tid >> 7;
    float v = (k < 256) ? Wcat[k * 128 + c] : proj[(k - 256) * 128 + c];
    WpT[c * 512 + k] = f2bf_rn(v);
  }
  if (tid < 128) bsum[tid] = Wcb[tid] + bias[tid] + prb[tid];
}

// ---- K0b: masks f32 -> pre-swizzled wave lane-masks (u64). grid 512x512 ----
// swz[t][it][e] bit l = G[t*16 + (l&15)][it*32 + (l>>4)*8 + e] != 0
__global__ __launch_bounds__(512) void k_bits(
    const float* __restrict__ Dg, const float* __restrict__ Sg,
    unsigned long long* __restrict__ swzD, unsigned long long* __restrict__ swzS)
{
  const int g = blockIdx.x & 1, t = blockIdx.x >> 1;
  const float* G = g ? Sg : Dg;
  unsigned long long* swz = g ? swzS : swzD;
  const int w = threadIdx.x >> 6, lane = threadIdx.x & 63;
  const int mr = lane & 15, grp = lane >> 4;
  const float* row = G + (size_t)(t * 16 + mr) * NN + grp * 8;
  #pragma unroll 2
  for (int it = w * 16; it < w * 16 + 16; ++it) {
    const float4 a = *(const float4*)(row + it * 32);
    const float4 b = *(const float4*)(row + it * 32 + 4);
    unsigned long long m0 = __ballot(a.x != 0.f);
    unsigned long long m1 = __ballot(a.y != 0.f);
    unsigned long long m2 = __ballot(a.z != 0.f);
    unsigned long long m3 = __ballot(a.w != 0.f);
    unsigned long long m4 = __ballot(b.x != 0.f);
    unsigned long long m5 = __ballot(b.y != 0.f);
    unsigned long long m6 = __ballot(b.z != 0.f);
    unsigned long long m7 = __ballot(b.w != 0.f);
    if (lane == 0) {
      unsigned long long* dst = swz + ((size_t)t * 128 + it) * 8;
      u64x2 p0 = {m0, m1}, p1 = {m2, m3}, p2 = {m4, m5}, p3 = {m6, m7};
      *(u64x2*)(dst)     = p0;
      *(u64x2*)(dst + 2) = p1;
      *(u64x2*)(dst + 4) = p2;
      *(u64x2*)(dst + 6) = p3;
    }
  }
}

// ---- K1: score GEMM + f2 + packed exp tables. grid 256 x 512 ----
__global__ __launch_bounds__(512) void k_score(
    const unsigned short* __restrict__ Xb, const unsigned short* __restrict__ WwT,
    const float* __restrict__ Wb, const float* __restrict__ wu,
    const float* __restrict__ wv,
    unsigned short* __restrict__ scT, float* __restrict__ f2,
    unsigned int* __restrict__ EEp)
{
  const int n0 = blockIdx.x * 16;
  const int h = threadIdx.x >> 6, lane = threadIdx.x & 63;
  const int mr = lane & 15, grp = lane >> 4;
  const unsigned short* ap  = Xb  + (size_t)(n0 + mr) * 256;
  const unsigned short* bpp = WwT + (size_t)(h * 16 + mr) * 256;
  f32x4 acc = {0.f, 0.f, 0.f, 0.f};
  #pragma unroll
  for (int ks = 0; ks < 8; ++ks) {
    bf16x8 a = *(const bf16x8*)(ap  + ks * 32 + grp * 8);
    bf16x8 b = *(const bf16x8*)(bpp + ks * 32 + grp * 8);
    acc = __builtin_amdgcn_mfma_f32_16x16x32_bf16(a, b, acc, 0, 0, 0);
  }
  const float wb = Wb[h * 16 + mr];
  float sc[4];
  #pragma unroll
  for (int r = 0; r < 4; ++r) sc[r] = acc[r] + wb;  // score[n0+grp*4+r][h*16+mr]

  uint2 st;  // scT[h*16+mr][n0+grp*4 .. +3] bf16
  st.x = (unsigned)f2bf_rn(sc[0]) | ((unsigned)f2bf_rn(sc[1]) << 16);
  st.y = (unsigned)f2bf_rn(sc[2]) | ((unsigned)f2bf_rn(sc[3]) << 16);
  *(uint2*)(scT + (size_t)(h * 16 + mr) * NN + n0 + grp * 4) = st;

  const float uw = wu[h * 16 + mr], vw = wv[h * 16 + mr];
  float t1[4], t2[4];
  #pragma unroll
  for (int r = 0; r < 4; ++r) { t1[r] = sc[r] * uw; t2[r] = sc[r] * vw; }
  #pragma unroll
  for (int m = 1; m < 16; m <<= 1) {
    #pragma unroll
    for (int r = 0; r < 4; ++r) {
      t1[r] += __shfl_xor(t1[r], m, 64);
      t2[r] += __shfl_xor(t2[r], m, 64);
    }
  }
  if (mr == 0) {
    *(float4*)(f2 + h * NN + n0 + grp * 4) = make_float4(t2[0], t2[1], t2[2], t2[3]);
    uint4 ep;
    ep.x = epack(t1[0]); ep.y = epack(t1[1]);
    ep.z = epack(t1[2]); ep.w = epack(t1[3]);
    *(uint4*)(EEp + h * NN + n0 + grp * 4) = ep;
  }
}

// ---- K2: fused dual-graph masked softmax attention + output GEMM ----
// grid 256 (i-tiles) x 512 (8 waves = 8 heads). No LDS / no barriers in the
// main loop; masks = wave-uniform u64 via scalar loads + v_cndmask.
__global__ __launch_bounds__(512, 4) void k_attn_out(
    const unsigned long long* __restrict__ swzD,
    const unsigned long long* __restrict__ swzS,
    const unsigned short* __restrict__ scT, const unsigned int* __restrict__ EEp,
    const float* __restrict__ f2, const unsigned short* __restrict__ Xb,
    const unsigned short* __restrict__ WpT, const float* __restrict__ bsum,
    float* __restrict__ out)
{
  __shared__ unsigned short catT[16][520];  // [row][ S(128) | D(128) | X(256) ]
  const int i0 = blockIdx.x * 16;
  const int tid = threadIdx.x;
  {  // stage X rows -> catT cols 256..511
    const int r = tid >> 5, x0 = (tid & 31) * 8;
    *(bf16x8*)(&catT[r][256 + x0]) = *(const bf16x8*)(Xb + (size_t)(i0 + r) * 256 + x0);
  }
  const int h = tid >> 6, lane = tid & 63;
  const int mr = lane & 15, grp = lane >> 4;

  const float f2v = f2[h * NN + i0 + mr];
  const float Af = __builtin_amdgcn_exp2f(f2v * LOG2E);
  const float Bf = __builtin_amdgcn_exp2f(0.3f * f2v * LOG2E);
  const float Tf = __builtin_amdgcn_exp2f(-f2v * LOG2E);

  const unsigned int* eep = EEp + h * NN;
  const unsigned short* bp = scT + (size_t)(h * 16 + mr) * NN;
  const unsigned long long* mD = swzD + (size_t)blockIdx.x * 1024;
  const unsigned long long* mS = swzS + (size_t)blockIdx.x * 1024;

  f32x4 accD = {0.f,0.f,0.f,0.f}, accS = {0.f,0.f,0.f,0.f};
  f32x4 dn1D = {0.f,0.f,0.f,0.f}, dn1S = {0.f,0.f,0.f,0.f};
  const bf16x8 ones = {(short)0x3F80, (short)0x3F80, (short)0x3F80, (short)0x3F80,
                       (short)0x3F80, (short)0x3F80, (short)0x3F80, (short)0x3F80};

  for (int it = 0; it < 128; ++it) {
    const int jl = it * 32 + grp * 8;
    const uint4 ea = *(const uint4*)(eep + jl);
    const uint4 eb = *(const uint4*)(eep + jl + 4);
    const bf16x8 bfrag = *(const bf16x8*)(bp + jl);
    const u64x4 md0 = *(const u64x4*)(mD + it * 8);      // uniform -> s_load
    const u64x4 md1 = *(const u64x4*)(mD + it * 8 + 4);
    const u64x4 ms0 = *(const u64x4*)(mS + it * 8);
    const u64x4 ms1 = *(const u64x4*)(mS + it * 8 + 4);
    float pd[8], ps[8];
    #pragma unroll
    for (int e = 0; e < 8; ++e) {
      const unsigned int u = (e < 4) ? (&ea.x)[e] : (&eb.x)[e - 4];
      const float E1 = __uint_as_float(u << 16);
      const float E3 = __uint_as_float(u & 0xFFFF0000u);
      const float qa = E1 * Af, qb = E3 * Bf;
      const float q = (E1 >= Tf) ? qa : qb;
      const unsigned long long mdE = (e < 4) ? md0[e] : md1[e - 4];
      const unsigned long long msE = (e < 4) ? ms0[e] : ms1[e - 4];
      float eD, eS;
      asm("v_cndmask_b32 %0, 0, %1, %2" : "=v"(eD) : "v"(q), "s"(mdE));
      asm("v_cndmask_b32 %0, 0, %1, %2" : "=v"(eS) : "v"(q), "s"(msE));
      pd[e] = eD; ps[e] = eS;
    }
    union { unsigned int u[4]; bf16x8 v; } AD, AS;
    #pragma unroll
    for (int q2 = 0; q2 < 4; ++q2) {
      AD.u[q2] = pk_trunc(pd[2 * q2], pd[2 * q2 + 1]);
      AS.u[q2] = pk_trunc(ps[2 * q2], ps[2 * q2 + 1]);
    }
    accD = __builtin_amdgcn_mfma_f32_16x16x32_bf16(AD.v, bfrag, accD, 0, 0, 0);
    accS = __builtin_amdgcn_mfma_f32_16x16x32_bf16(AS.v, bfrag, accS, 0, 0, 0);
    dn1D = __builtin_amdgcn_mfma_f32_16x16x32_bf16(AD.v, ones, dn1D, 0, 0, 0);
    dn1S = __builtin_amdgcn_mfma_f32_16x16x32_bf16(AS.v, ones, dn1S, 0, 0, 0);
  }

  // C layout: col=mr, row=grp*4+r. dn1*[r] = that row's denominator (all cols equal).
  #pragma unroll
  for (int r = 0; r < 4; ++r) {
    const int row = grp * 4 + r;
    const float vS = accS[r] * __builtin_amdgcn_rcpf(fmaxf(dn1S[r], 1e-30f));
    const float vD = accD[r] * __builtin_amdgcn_rcpf(fmaxf(dn1D[r], 1e-30f));
    catT[row][h * 16 + mr]       = f2bf_rn(vS);
    catT[row][128 + h * 16 + mr] = f2bf_rn(vD);
  }
  __syncthreads();

  // phase B: out[16][128] = catT[16][512] @ W'[512][128] + bsum
  f32x4 o = {0.f, 0.f, 0.f, 0.f};
  const unsigned short* wp = WpT + (size_t)(h * 16 + mr) * 512;
  #pragma unroll
  for (int ks = 0; ks < 16; ++ks) {
    bf16x8 a = *(const bf16x8*)(&catT[mr][ks * 32 + grp * 8]);
    bf16x8 b = *(const bf16x8*)(wp + ks * 32 + grp * 8);
    o = __builtin_amdgcn_mfma_f32_16x16x32_bf16(a, b, o, 0, 0, 0);
  }
  const float bs = bsum[h * 16 + mr];
  #pragma unroll
  for (int r = 0; r < 4; ++r)
    out[(size_t)(i0 + grp * 4 + r) * 128 + h * 16 + mr] = o[r] + bs;
}

extern "C" void kernel_launch(void* const* d_in, const int* in_sizes, int n_in,
                              void* d_out, int out_size, void* d_ws, size_t ws_size,
                              hipStream_t stream) {
  const float* X    = (const float*)d_in[0];
  const float* Dg   = (const float*)d_in[1];
  const float* Sg   = (const float*)d_in[2];
  const float* Ww   = (const float*)d_in[3];
  const float* Wb   = (const float*)d_in[4];
  const float* wu   = (const float*)d_in[5];
  const float* wv   = (const float*)d_in[6];
  const float* Wcat = (const float*)d_in[7];
  const float* Wcb  = (const float*)d_in[8];
  const float* bias = (const float*)d_in[9];
  const float* proj = (const float*)d_in[10];
  const float* prb  = (const float*)d_in[11];
  float* out = (float*)d_out;

  char* ws = (char*)d_ws;
  unsigned short* Xb   = (unsigned short*)(ws);              // 2 MB
  unsigned short* scT  = (unsigned short*)(ws + 0x200000);   // 1 MB
  float*          f2   = (float*)(ws + 0x300000);            // 128 KB
  unsigned int*   EEp  = (unsigned int*)(ws + 0x320000);     // 128 KB
  unsigned short* WwT  = (unsigned short*)(ws + 0x340000);   // 64 KB
  unsigned short* WpT  = (unsigned short*)(ws + 0x350000);   // 128 KB
  float*          bsum = (float*)(ws + 0x370000);            // 512 B
  unsigned long long* swzD = (unsigned long long*)(ws + 0x380000);  // 2 MB
  unsigned long long* swzS = (unsigned long long*)(ws + 0x580000);  // 2 MB

  k_prep<<<dim3(512), dim3(256), 0, stream>>>(X, Ww, Wcat, proj, Wcb, bias, prb,
                                              Xb, WwT, WpT, bsum);
  k_bits<<<dim3(512), dim3(512), 0, stream>>>(Dg, Sg, swzD, swzS);
  k_score<<<dim3(256), dim3(512), 0, stream>>>(Xb, WwT, Wb, wu, wv, scT, f2, EEp);
  k_attn_out<<<dim3(256), dim3(512), 0, stream>>>(swzD, swzS, scT, EEp, f2,
                                                  Xb, WpT, bsum, out);
}